// Round 7
// baseline (616.302 us; speedup 1.0000x reference)
//
#include <hip/hip_runtime.h>
#include <stdint.h>

typedef float f32x4 __attribute__((ext_vector_type(4)));
typedef float f32x16 __attribute__((ext_vector_type(16)));
typedef __bf16 bf16x8 __attribute__((ext_vector_type(8)));
typedef unsigned short ushort_t;
typedef ushort_t ushortx8 __attribute__((ext_vector_type(8)));
typedef ushort_t ushortx4 __attribute__((ext_vector_type(4)));
typedef uint32_t u32x2 __attribute__((ext_vector_type(2)));

#define DEV static __device__ __forceinline__

DEV ushort_t f2bf(float f) {
  union { float f; uint32_t u; } v; v.f = f;
  uint32_t u = v.u;
  return (ushort_t)((u + 0x7FFFu + ((u >> 16) & 1u)) >> 16);
}

DEV uint32_t pkbf(float a, float b) {
  __bf16 x = (__bf16)a, y = (__bf16)b;
  return (uint32_t)__builtin_bit_cast(unsigned short, x) |
         ((uint32_t)__builtin_bit_cast(unsigned short, y) << 16);
}

DEV void cp16(const void* g, void* l) {
  __builtin_amdgcn_global_load_lds((const __attribute__((address_space(1))) unsigned int*)g,
                                   (__attribute__((address_space(3))) unsigned int*)l,
                                   16, 0, 0);
}

DEV f32x4 mfma16(bf16x8 a, bf16x8 b, f32x4 c) {
  return __builtin_amdgcn_mfma_f32_16x16x32_bf16(a, b, c, 0, 0, 0);
}

DEV f32x16 mfma32(bf16x8 a, bf16x8 b, f32x16 c) {
  return __builtin_amdgcn_mfma_f32_32x32x16_bf16(a, b, c, 0, 0, 0);
}

// ------------- merged prep: cvt x (blocks 0..4095), 4 weight transposes -----
__global__ __launch_bounds__(256) void k_prep(
    const float* __restrict__ x, ushort_t* __restrict__ xb,
    const float* __restrict__ wq, const float* __restrict__ wk,
    const float* __restrict__ wv, const float* __restrict__ wo,
    ushort_t* __restrict__ wqkvT, ushort_t* __restrict__ woT) {
  __shared__ float tile[32][33];
  int b = blockIdx.x;
  if (b < 4096) {
    size_t idx = ((size_t)b * 256 + threadIdx.x) * 8;
    const float4* src = (const float4*)(x + idx);
    float4 a = src[0], c = src[1];
    ushortx8 o;
    o[0] = f2bf(a.x); o[1] = f2bf(a.y); o[2] = f2bf(a.z); o[3] = f2bf(a.w);
    o[4] = f2bf(c.x); o[5] = f2bf(c.y); o[6] = f2bf(c.z); o[7] = f2bf(c.w);
    *(ushortx8*)(xb + idx) = o;
  } else {
    int t = b - 4096;
    int which = t >> 10;  // 0=wq 1=wk 2=wv 3=wo
    const float* src = (which == 0) ? wq : (which == 1) ? wk : (which == 2) ? wv : wo;
    ushort_t* dst = (which == 0) ? wqkvT
                    : (which == 1) ? wqkvT + 1024 * 1024
                    : (which == 2) ? wqkvT + 2 * 1024 * 1024
                                   : woT;
    int tt = t & 1023;
    int c0 = (tt & 31) * 32, r0 = (tt >> 5) * 32;
    int tx = threadIdx.x & 31, ty = threadIdx.x >> 5;
#pragma unroll
    for (int i = ty; i < 32; i += 8)
      tile[i][tx] = src[(size_t)(r0 + i) * 1024 + c0 + tx];
    __syncthreads();
#pragma unroll
    for (int i = ty; i < 32; i += 8)
      dst[(size_t)(c0 + i) * 1024 + r0 + tx] = f2bf(tile[tx][i]);
  }
}

// ---------------- transpose v: [bh][2048][64] -> [bh][64][2048] bf16 --------
__global__ __launch_bounds__(256) void k_transpose_v(const ushort_t* __restrict__ vw,
                                                     ushort_t* __restrict__ vtw) {
  __shared__ ushort_t t[64][72];
  int tid = threadIdx.x;
  int bh = blockIdx.y, s0 = blockIdx.x * 64;
#pragma unroll
  for (int n = 0; n < 2; ++n) {
    int row = (tid >> 3) + n * 32, ch = (tid & 7) * 8;
    *(ushortx8*)&t[row][ch] =
        *(const ushortx8*)&vw[((size_t)bh * 2048 + s0 + row) * 64 + ch];
  }
  __syncthreads();
#pragma unroll
  for (int n = 0; n < 2; ++n) {
    int dh = (tid >> 3) + n * 32, sc = (tid & 7) * 8;
    ushortx8 o;
#pragma unroll
    for (int k = 0; k < 8; ++k) o[k] = t[sc + k][dh];
    *(ushortx8*)&vtw[((size_t)bh * 64 + dh) * 2048 + s0 + sc] = o;
  }
}

// ---------------- GEMM (unchanged from R6) ----------------
template <int MODE>
__global__ __launch_bounds__(256, 2) void k_gemm(
    const ushort_t* __restrict__ A, const ushort_t* __restrict__ Bt,
    const float* __restrict__ b0, const float* __restrict__ b1,
    const float* __restrict__ b2, ushort_t* __restrict__ qw,
    ushort_t* __restrict__ kw, ushort_t* __restrict__ vw,
    float* __restrict__ outf) {
  const int K = 1024;
  __shared__ ushort_t As[128 * 32];
  __shared__ ushort_t Bs[128 * 32];
  int tid = threadIdx.x;
  int w = tid >> 6, lane = tid & 63, l16 = lane & 15, lg = lane >> 4;
  int m0 = blockIdx.x * 128, n0 = blockIdx.y * 128;
  int wm = (w >> 1) * 64, wn = (w & 1) * 64;
  f32x4 acc[4][4] = {};

  const ushort_t* Ag = A + (size_t)(m0 + (tid >> 2)) * K + (tid & 3) * 8;
  const ushort_t* Bg = Bt + (size_t)(n0 + (tid >> 2)) * K + (tid & 3) * 8;

  for (int k0 = 0; k0 < K; k0 += 32) {
    cp16(Ag + k0, As + w * 512);
    cp16(Ag + k0 + 64 * K, As + 2048 + w * 512);
    cp16(Bg + k0, Bs + w * 512);
    cp16(Bg + k0 + 64 * K, Bs + 2048 + w * 512);
    __syncthreads();
    bf16x8 af[4], bfr[4];
#pragma unroll
    for (int i = 0; i < 4; ++i)
      af[i] = *(const bf16x8*)&As[(wm + i * 16 + l16) * 32 + lg * 8];
#pragma unroll
    for (int j = 0; j < 4; ++j)
      bfr[j] = *(const bf16x8*)&Bs[(wn + j * 16 + l16) * 32 + lg * 8];
#pragma unroll
    for (int i = 0; i < 4; ++i)
#pragma unroll
      for (int j = 0; j < 4; ++j)
        acc[i][j] = mfma16(af[i], bfr[j], acc[i][j]);
    __syncthreads();
  }

  if (MODE == 0) {
    const float QSCALE = 0.18033688011112042f;  // (1/sqrt(64)) * log2(e)
    int p = m0 >> 10;
    const float* bias = (p == 0) ? b0 : (p == 1) ? b1 : b2;
    ushort_t* dst = (p == 0) ? qw : (p == 1) ? kw : vw;
    float qs = (p == 0) ? QSCALE : 1.0f;
    int cbase = m0 & 1023;
#pragma unroll
    for (int i = 0; i < 4; ++i) {
      int oc = cbase + wm + i * 16 + lg * 4;
      int h = oc >> 6, dh0 = oc & 63;
      float4 bb = *(const float4*)&bias[oc];
#pragma unroll
      for (int j = 0; j < 4; ++j) {
        int tok = n0 + wn + j * 16 + l16;
        size_t base =
            ((size_t)((tok >> 11) * 16 + h) * 2048 + (tok & 2047)) * 64 + dh0;
        ushortx4 pk;
        pk[0] = f2bf((acc[i][j][0] + bb.x) * qs);
        pk[1] = f2bf((acc[i][j][1] + bb.y) * qs);
        pk[2] = f2bf((acc[i][j][2] + bb.z) * qs);
        pk[3] = f2bf((acc[i][j][3] + bb.w) * qs);
        *(ushortx4*)&dst[base] = pk;
      }
    }
  } else {
#pragma unroll
    for (int j = 0; j < 4; ++j) {
      int col = n0 + wn + j * 16 + l16;
      float bb = b0[col];
#pragma unroll
      for (int i = 0; i < 4; ++i) {
#pragma unroll
        for (int r = 0; r < 4; ++r) {
          int row = m0 + wm + i * 16 + lg * 4 + r;
          outf[(size_t)row * 1024 + col] = acc[i][j][r] + bb;
        }
      }
    }
  }
}

// ---------------- flash attention, 32x32 MFMA version ----------------
// grid 512 blocks x 256 thr (4 waves); XCD swizzle as before. Wave owns 64 q
// (2 strips of 32). Per 32-key group: QK (A=K, B=Q, mfma 32x32x16; each
// K-frag shared by both strips), softmax (col=q C-layout -> l-sum is in-lane
// adds, no ones-MFMA), P -> per-wave LDS (b64 quad writes, XOR swizzle),
// PV (A=P, B=V; each V-frag shared by both strips). LDS b128 reads per
// wave-tile(64q): 48 vs 80 in the 16x16 design -> LDS-pipe cut 1.67x.
// A-layout 32x32x16: m=lane&31, k=(lane>>5)*8+j; B symmetric; C row =
// (reg&3)+8*(reg>>2)+4*(lane>>5), col=lane&31.
__global__ __launch_bounds__(256, 3) void k_attn(
    const ushort_t* __restrict__ qg, const ushort_t* __restrict__ kg,
    const ushort_t* __restrict__ vtg, ushort_t* __restrict__ att) {
  __shared__ ushort_t Ks[128 * 64];       // [key][dh], chunk8 ^= key&7   16KB
  __shared__ ushort_t Vs[64 * 128];       // [dh][key], chunk16 ^= dh&15  16KB
  __shared__ ushort_t Ps[4][2][32 * 32];  // per-wave/strip [q][key]      16KB
  int tid = threadIdx.x;
  int w = tid >> 6, lane = tid & 63, l32 = lane & 31, half = lane >> 5;
  int i = blockIdx.x;
  int bh = (i & 7) * 8 + ((i >> 3) & 7);
  int q0 = (i >> 6) * 256;
  const ushort_t* qh = qg + (size_t)bh * 2048 * 64;

  const ushort_t* kstage = kg + (size_t)bh * 2048 * 64 + (size_t)(tid >> 3) * 64 +
                           (size_t)(((tid & 7) ^ ((tid >> 3) & 7)) * 8);
  const ushort_t* vstage = vtg + (size_t)bh * 64 * 2048 + (size_t)(tid >> 4) * 2048 +
                           (size_t)(((tid & 15) ^ ((tid >> 4) & 15)) * 8);

  // Q as B-operand: B[k=dh=ks*16+half*8+j][n=q=l32], loaded once
  bf16x8 qf[2][4];
#pragma unroll
  for (int st = 0; st < 2; ++st)
#pragma unroll
    for (int ks = 0; ks < 4; ++ks)
      qf[st][ks] = *(const bf16x8*)(qh +
                                    (size_t)(q0 + w * 64 + st * 32 + l32) * 64 +
                                    ks * 16 + half * 8);

  f32x16 o[2][2] = {};  // [strip][dh-tile]
  float lsum[2] = {0.f, 0.f};
  int swz = (l32 >> 1) & 3;

  for (int kb = 0; kb < 2048; kb += 128) {
    __syncthreads();
#pragma unroll
    for (int j = 0; j < 4; ++j) {
      cp16(kstage + (size_t)(kb + j * 32) * 64, Ks + (j * 32 + w * 8) * 64);
      cp16(vstage + kb + (size_t)(j * 16) * 2048, Vs + (j * 16 + w * 4) * 128);
    }
    __syncthreads();

#pragma unroll
    for (int g = 0; g < 4; ++g) {
      // K fragments for this 32-key group (shared by both strips)
      bf16x8 kf[4];
#pragma unroll
      for (int ks = 0; ks < 4; ++ks)
        kf[ks] = *(const bf16x8*)&Ks[(g * 32 + l32) * 64 +
                                     (((2 * ks + half) ^ (l32 & 7)) * 8)];
#pragma unroll
      for (int st = 0; st < 2; ++st) {
        f32x16 sc = {};
#pragma unroll
        for (int ks = 0; ks < 4; ++ks) sc = mfma32(kf[ks], qf[st][ks], sc);
        // softmax: exp in place, in-lane l accumulation (lane's col = one q)
        float ls = 0.f;
#pragma unroll
        for (int r = 0; r < 16; ++r) {
          sc[r] = __builtin_amdgcn_exp2f(sc[r]);
          ls += sc[r];
        }
        lsum[st] += ls;
        // P quads -> b64 writes: keys 8*q2+4*half+(0..3) at row q=l32
#pragma unroll
        for (int q2 = 0; q2 < 4; ++q2) {
          u32x2 pk;
          pk[0] = pkbf(sc[q2 * 4 + 0], sc[q2 * 4 + 1]);
          pk[1] = pkbf(sc[q2 * 4 + 2], sc[q2 * 4 + 3]);
          *(u32x2*)&Ps[w][st][l32 * 32 + ((q2 ^ swz) * 8) + half * 4] = pk;
        }
      }
      // PV over this group's 32 keys: each vf shared by both strips
#pragma unroll
      for (int ks2 = 0; ks2 < 2; ++ks2) {
        int pofs = l32 * 32 + (((2 * ks2 + half) ^ swz) * 8);
        bf16x8 pf0 = *(const bf16x8*)&Ps[w][0][pofs];
        bf16x8 pf1 = *(const bf16x8*)&Ps[w][1][pofs];
#pragma unroll
        for (int dt = 0; dt < 2; ++dt) {
          bf16x8 vf = *(const bf16x8*)&Vs[(dt * 32 + l32) * 128 +
                                          (((4 * g + 2 * ks2 + half) ^
                                            (l32 & 15)) * 8)];
          o[0][dt] = mfma32(pf0, vf, o[0][dt]);
          o[1][dt] = mfma32(pf1, vf, o[1][dt]);
        }
      }
    }
  }

  // epilogue: combine half-l, broadcast 1/l via per-wave LDS, write O
  float* lp = (float*)&Ps[w][0][0];
#pragma unroll
  for (int st = 0; st < 2; ++st) {
    float lt = lsum[st] + __shfl_xor(lsum[st], 32);
    if (half == 0) lp[st * 32 + l32] = __builtin_amdgcn_rcpf(lt);
  }
  int bi = bh >> 4, h = bh & 15;
#pragma unroll
  for (int st = 0; st < 2; ++st) {
    float linv[16];
#pragma unroll
    for (int r = 0; r < 16; ++r)
      linv[r] = lp[st * 32 + ((r & 3) + 8 * (r >> 2) + 4 * half)];
#pragma unroll
    for (int dt = 0; dt < 2; ++dt)
#pragma unroll
      for (int r = 0; r < 16; ++r) {
        int tok = q0 + w * 64 + st * 32 + (r & 3) + 8 * (r >> 2) + 4 * half;
        att[(size_t)(bi * 2048 + tok) * 1024 + h * 64 + dt * 32 + l32] =
            f2bf(o[st][dt][r] * linv[r]);
      }
  }
}

// ---------------- host ----------------
extern "C" void kernel_launch(void* const* d_in, const int* in_sizes, int n_in,
                              void* d_out, int out_size, void* d_ws, size_t ws_size,
                              hipStream_t stream) {
  const float* x = (const float*)d_in[0];
  const float* wq = (const float*)d_in[1];
  const float* bq = (const float*)d_in[2];
  const float* wk = (const float*)d_in[3];
  const float* bk = (const float*)d_in[4];
  const float* wv = (const float*)d_in[5];
  const float* bv = (const float*)d_in[6];
  const float* wo = (const float*)d_in[7];
  const float* bo = (const float*)d_in[8];
  float* out = (float*)d_out;

  char* ws = (char*)d_ws;
  ushort_t* xb = (ushort_t*)(ws);                       // 16 MiB
  ushort_t* wqkvT = (ushort_t*)(ws + 16777216);         // 6 MiB ([3072][1024])
  ushort_t* woT = (ushort_t*)(ws + 23068672);           // 2 MiB ([1024][1024])
  ushort_t* qw = (ushort_t*)(ws + 25165824);            // 16 MiB
  ushort_t* kw = (ushort_t*)(ws + 41943040);            // 16 MiB
  ushort_t* vtw = (ushort_t*)(ws + 58720256);           // 16 MiB
  ushort_t* att = (ushort_t*)(ws + 75497472);           // 16 MiB
  ushort_t* vw = att;  // vw is dead before att is written

  k_prep<<<dim3(8192), dim3(256), 0, stream>>>(x, xb, wq, wk, wv, wo, wqkvT, woT);

  k_gemm<0><<<dim3(24, 64), dim3(256), 0, stream>>>(
      wqkvT, xb, bq, bk, bv, qw, kw, vw, nullptr);

  k_transpose_v<<<dim3(32, 64), dim3(256), 0, stream>>>(vw, vtw);

  k_attn<<<dim3(512), dim3(256), 0, stream>>>(qw, kw, vtw, att);

  k_gemm<1><<<dim3(64, 8), dim3(256), 0, stream>>>(
      att, woT, bo, nullptr, nullptr, nullptr, nullptr, nullptr, out);
}